// Round 12
// baseline (2526.918 us; speedup 1.0000x reference)
//
#include <hip/hip_runtime.h>
#include <math.h>

// Problem constants
#define Bsz 32
#define Tt  512
#define Isz 256
#define Hsz 512
#define G3  1536
#define Osz 128

// Recurrence config (round-6 proven structure): 256 blocks = 32 batches x 8
// col-groups; 512 threads/block. Device-coherent (sc0 sc1) gen-tagged pairs.
// Inner loop uses v_pk_fma_f32 (packed dual f32 FMA) to halve VALU issue.
#define NBLK 256
#define TPB  512
#define G0_L0 1u
#define G0_L1 4096u
#define POLL_GUARD (1 << 22)

typedef float f2  __attribute__((ext_vector_type(2)));
typedef float f4  __attribute__((ext_vector_type(4)));
typedef float f32x4 __attribute__((ext_vector_type(4)));
typedef _Float16 half8_t __attribute__((ext_vector_type(8)));
typedef _Float16 half4_t __attribute__((ext_vector_type(4)));
typedef unsigned int u32;
typedef u32 u32x2 __attribute__((ext_vector_type(2)));

__device__ __forceinline__ float sigf(float x) { return 1.0f / (1.0f + expf(-x)); }

// ---------------- f32 -> f16 conversion (weights, exact RNE casts) ----------------
__global__ void f32_to_f16(const float* __restrict__ in, _Float16* __restrict__ out, int n4) {
    int i = threadIdx.x + blockIdx.x * blockDim.x;
    int stride = blockDim.x * gridDim.x;
    for (int k = i; k < n4; k += stride) {
        float4 v = reinterpret_cast<const float4*>(in)[k];
        half4_t o;
        o[0] = (_Float16)v.x; o[1] = (_Float16)v.y;
        o[2] = (_Float16)v.z; o[3] = (_Float16)v.w;
        reinterpret_cast<half4_t*>(out)[k] = o;
    }
}

// ---------------- init pbuf: slot0 = (h0=0, gen0), slot1 = invalid ----------------
__global__ void init_pbuf(u32x2* pbuf, u32 gen0) {
    int i = threadIdx.x + blockIdx.x * blockDim.x;
    const int n = Bsz * Hsz;
    for (; i < n; i += gridDim.x * blockDim.x) {
        pbuf[i]     = (u32x2){0u, gen0};
        pbuf[n + i] = (u32x2){0u, 0u};
    }
}

// ---------------- persistent GRU recurrence (one layer), batch-split ----------------
// Block (b,p): batch b, h-cols [p*64, p*64+64). Thread (jl=tid>>3, kc=tid&7):
// col j=p*64+jl, k-range [kc*64, +64). 96 f2 weight pairs per thread; compute
// via v_pk_fma_f32 (2 FMAs/inst, f32-exact).
__global__ void __launch_bounds__(TPB)
__attribute__((amdgpu_waves_per_eu(2, 2)))
gru_rec(
    const float* __restrict__ xp,    // [B*T, 3H] (includes b_ih)
    const float* __restrict__ Whh,   // [3H, H]
    const float* __restrict__ bhh,   // [3H]
    float* __restrict__ hall,        // [B*T, H]
    u32x2* __restrict__ pbuf,        // [2][B*H] (val,gen)
    float* __restrict__ hid_out,     // [B*H]
    u32 g0)
{
    const int tid = threadIdx.x;
    const int b   = blockIdx.x & 31;
    const int p   = blockIdx.x >> 5;
    const int jl  = tid >> 3;
    const int kc  = tid & 7;
    const int j   = p * 64 + jl;

    __shared__ float hsh[8 * 68];

    // ---- load weights as f2 pairs: rows {g*H+j}, k in [kc*64, +64) ----
    f2 wreg2[3][32];
    #pragma unroll
    for (int g = 0; g < 3; ++g) {
        const f2* wp2 = reinterpret_cast<const f2*>(Whh + (size_t)(g * Hsz + j) * Hsz + kc * 64);
        #pragma unroll
        for (int q = 0; q < 32; ++q) wreg2[g][q] = wp2[q];
    }
    #pragma unroll
    for (int g = 0; g < 3; ++g)
        #pragma unroll
        for (int q = 0; q < 32; ++q)
            asm volatile("" : "+v"(wreg2[g][q]));

    const float bh0 = bhh[0 * Hsz + j];
    const float bh1 = bhh[1 * Hsz + j];
    const float bh2 = bhh[2 * Hsz + j];

    for (int t = 0; t < Tt; ++t) {
        const u32 rg = g0 + (u32)t;
        const u32 wg = rg + 1u;
        const u32x2* src = pbuf + (size_t)(t & 1) * (Bsz * Hsz) + b * Hsz;
        u32x2*       dst = pbuf + (size_t)((t + 1) & 1) * (Bsz * Hsz) + b * Hsz;

        float xr = 0.f, xz = 0.f, xn = 0.f;
        if (kc == 0) {
            const float* pp = xp + (size_t)(b * Tt + t) * G3;
            xr = pp[j];
            xz = pp[Hsz + j];
            xn = pp[2 * Hsz + j];
        }

        // ---- poll own pair, stage to LDS ----
        {
            const u32x2* sp = src + tid;
            int guard = 0;
            for (;;) {
                u32x2 pr;
                asm volatile("global_load_dwordx2 %0, %1, off sc0 sc1\n\t"
                             "s_waitcnt vmcnt(0)"
                             : "=&v"(pr) : "v"(sp) : "memory");
                if (__all(pr[1] == rg) || ++guard > POLL_GUARD) {
                    hsh[(tid >> 6) * 68 + (tid & 63)] = __uint_as_float(pr[0]);
                    break;
                }
                __builtin_amdgcn_s_sleep(1);
            }
        }
        __syncthreads();

        // ---- compute: 3 gates over k in [kc*64, +64) via packed FMA ----
        f2 c0 = (f2){0.f, 0.f}, c1 = (f2){0.f, 0.f}, c2 = (f2){0.f, 0.f};
        {
            const f2* hp2 = reinterpret_cast<const f2*>(hsh + kc * 68);
            #pragma unroll
            for (int q = 0; q < 32; ++q) {
                f2 hv = hp2[q];
                asm volatile("v_pk_fma_f32 %0, %1, %2, %0" : "+v"(c0) : "v"(wreg2[0][q]), "v"(hv));
                asm volatile("v_pk_fma_f32 %0, %1, %2, %0" : "+v"(c1) : "v"(wreg2[1][q]), "v"(hv));
                asm volatile("v_pk_fma_f32 %0, %1, %2, %0" : "+v"(c2) : "v"(wreg2[2][q]), "v"(hv));
            }
        }
        float a0 = c0[0] + c0[1];
        float a1 = c1[0] + c1[1];
        float a2 = c2[0] + c2[1];

        // reduce across the 8 kc lanes
        #pragma unroll
        for (int off = 1; off < 8; off <<= 1) {
            a0 += __shfl_xor(a0, off, 64);
            a1 += __shfl_xor(a1, off, 64);
            a2 += __shfl_xor(a2, off, 64);
        }

        if (kc == 0) {
            float rr = sigf(xr + a0 + bh0);
            float zz = sigf(xz + a1 + bh1);
            float nn = tanhf(xn + rr * (a2 + bh2));
            float ho = hsh[(j >> 6) * 68 + (j & 63)];
            float hv = (1.0f - zz) * nn + zz * ho;
            u32x2 pk = (u32x2){__float_as_uint(hv), wg};
            asm volatile("global_store_dwordx2 %0, %1, off sc0 sc1"
                         :: "v"(dst + j), "v"(pk) : "memory");
            hall[(size_t)(b * Tt + t) * Hsz + j] = hv;
            if (t == Tt - 1) hid_out[b * Hsz + j] = hv;
        }

        __syncthreads();
    }
}

// ---------------- f16-MFMA GEMM: C[M,N] = A[M,K]_f32 * Wh[N,K]_f16^T + bias ----
// Block 256 thr = 4 waves (2x2), block tile 128x128, wave tile 64x64 (4x4 of
// 16x16 MFMA tiles). Fragments loaded directly from global (contiguous 16B per
// lane for both operands); A converted f32->f16 in-register.
// Layouts (HW-verified, guide §3): A frag lane l: row=l&15, k=(l>>4)*8+i;
// B frag lane l: col=l&15, k=(l>>4)*8+i (= row l&15 of Wh, contiguous);
// C/D: col=lane&15, row=(lane>>4)*4+reg.
__global__ void __launch_bounds__(256) gemm_nt_mfma(
    const float* __restrict__ A,        // [M,K] f32
    const _Float16* __restrict__ Wh,    // [N,K] f16
    const float* __restrict__ bias,     // [N]
    float* __restrict__ C,              // [M,N]
    int M, int N, int K)
{
    const int tid = threadIdx.x;
    const int l   = tid & 63;
    const int w   = tid >> 6;
    const int wm  = w >> 1, wn = w & 1;
    const int m0  = blockIdx.y * 128 + wm * 64;
    const int n0  = blockIdx.x * 128 + wn * 64;
    const int lr  = l & 15;
    const int lk  = (l >> 4) * 8;

    f32x4 acc[4][4];
    #pragma unroll
    for (int mt = 0; mt < 4; ++mt)
        #pragma unroll
        for (int nt = 0; nt < 4; ++nt)
            acc[mt][nt] = (f32x4){0.f, 0.f, 0.f, 0.f};

    for (int ks = 0; ks < K; ks += 32) {
        half8_t af[4], bf[4];
        #pragma unroll
        for (int mt = 0; mt < 4; ++mt) {
            const float* pa = A + (size_t)(m0 + mt * 16 + lr) * K + ks + lk;
            float4 v0 = *reinterpret_cast<const float4*>(pa);
            float4 v1 = *reinterpret_cast<const float4*>(pa + 4);
            half8_t h;
            h[0] = (_Float16)v0.x; h[1] = (_Float16)v0.y;
            h[2] = (_Float16)v0.z; h[3] = (_Float16)v0.w;
            h[4] = (_Float16)v1.x; h[5] = (_Float16)v1.y;
            h[6] = (_Float16)v1.z; h[7] = (_Float16)v1.w;
            af[mt] = h;
        }
        #pragma unroll
        for (int nt = 0; nt < 4; ++nt)
            bf[nt] = *reinterpret_cast<const half8_t*>(Wh + (size_t)(n0 + nt * 16 + lr) * K + ks + lk);
        #pragma unroll
        for (int mt = 0; mt < 4; ++mt)
            #pragma unroll
            for (int nt = 0; nt < 4; ++nt)
                acc[mt][nt] = __builtin_amdgcn_mfma_f32_16x16x32_f16(af[mt], bf[nt], acc[mt][nt], 0, 0, 0);
    }

    #pragma unroll
    for (int nt = 0; nt < 4; ++nt) {
        const int colg = n0 + nt * 16 + lr;
        const float bb = bias[colg];
        #pragma unroll
        for (int mt = 0; mt < 4; ++mt) {
            #pragma unroll
            for (int r = 0; r < 4; ++r) {
                int rowg = m0 + mt * 16 + (l >> 4) * 4 + r;
                C[(size_t)rowg * N + colg] = acc[mt][nt][r] + bb;
            }
        }
    }
}

// ---------------- fp32 GEMM (FC only): C = A * W^T + bias ----------------
#define GM 64
#define GN 64
#define GK 16
__global__ void __launch_bounds__(256) gemm_nt_bias(
    const float* __restrict__ A, const float* __restrict__ W,
    const float* __restrict__ bias, float* __restrict__ C,
    int M, int N, int K)
{
    __shared__ float As[GK][GM];
    __shared__ float Bs[GK][GN];
    const int tid = threadIdx.x;
    const int n0 = blockIdx.x * GN;
    const int m0 = blockIdx.y * GM;
    const int tn = tid & 15;
    const int tm = tid >> 4;
    const int lrow = tid >> 2;
    const int lkq  = tid & 3;

    float acc[4][4];
    #pragma unroll
    for (int i = 0; i < 4; ++i)
        #pragma unroll
        for (int jj = 0; jj < 4; ++jj) acc[i][jj] = 0.0f;

    for (int k0 = 0; k0 < K; k0 += GK) {
        float4 av = *reinterpret_cast<const float4*>(&A[(size_t)(m0 + lrow) * K + k0 + lkq * 4]);
        float4 wv = *reinterpret_cast<const float4*>(&W[(size_t)(n0 + lrow) * K + k0 + lkq * 4]);
        __syncthreads();
        As[lkq * 4 + 0][lrow] = av.x; As[lkq * 4 + 1][lrow] = av.y;
        As[lkq * 4 + 2][lrow] = av.z; As[lkq * 4 + 3][lrow] = av.w;
        Bs[lkq * 4 + 0][lrow] = wv.x; Bs[lkq * 4 + 1][lrow] = wv.y;
        Bs[lkq * 4 + 2][lrow] = wv.z; Bs[lkq * 4 + 3][lrow] = wv.w;
        __syncthreads();
        #pragma unroll
        for (int k = 0; k < GK; ++k) {
            float4 a4 = *reinterpret_cast<const float4*>(&As[k][tm * 4]);
            float4 b4 = *reinterpret_cast<const float4*>(&Bs[k][tn * 4]);
            acc[0][0] = fmaf(a4.x, b4.x, acc[0][0]); acc[0][1] = fmaf(a4.x, b4.y, acc[0][1]);
            acc[0][2] = fmaf(a4.x, b4.z, acc[0][2]); acc[0][3] = fmaf(a4.x, b4.w, acc[0][3]);
            acc[1][0] = fmaf(a4.y, b4.x, acc[1][0]); acc[1][1] = fmaf(a4.y, b4.y, acc[1][1]);
            acc[1][2] = fmaf(a4.y, b4.z, acc[1][2]); acc[1][3] = fmaf(a4.y, b4.w, acc[1][3]);
            acc[2][0] = fmaf(a4.z, b4.x, acc[2][0]); acc[2][1] = fmaf(a4.z, b4.y, acc[2][1]);
            acc[2][2] = fmaf(a4.z, b4.z, acc[2][2]); acc[2][3] = fmaf(a4.z, b4.w, acc[2][3]);
            acc[3][0] = fmaf(a4.w, b4.x, acc[3][0]); acc[3][1] = fmaf(a4.w, b4.y, acc[3][1]);
            acc[3][2] = fmaf(a4.w, b4.z, acc[3][2]); acc[3][3] = fmaf(a4.w, b4.w, acc[3][3]);
        }
    }

    float4 bb = *reinterpret_cast<const float4*>(&bias[n0 + tn * 4]);
    #pragma unroll
    for (int i = 0; i < 4; ++i) {
        int m = m0 + tm * 4 + i;
        float4 o;
        o.x = acc[i][0] + bb.x; o.y = acc[i][1] + bb.y;
        o.z = acc[i][2] + bb.z; o.w = acc[i][3] + bb.w;
        *reinterpret_cast<float4*>(&C[(size_t)m * N + n0 + tn * 4]) = o;
    }
}

// ---------------- host launcher ----------------
extern "C" void kernel_launch(void* const* d_in, const int* in_sizes, int n_in,
                              void* d_out, int out_size, void* d_ws, size_t ws_size,
                              hipStream_t stream) {
    (void)in_sizes; (void)n_in; (void)out_size; (void)ws_size;
    const float* x    = (const float*)d_in[0];
    const float* Wih0 = (const float*)d_in[1];
    const float* Whh0 = (const float*)d_in[2];
    const float* bih0 = (const float*)d_in[3];
    const float* bhh0 = (const float*)d_in[4];
    const float* Wih1 = (const float*)d_in[5];
    const float* Whh1 = (const float*)d_in[6];
    const float* bih1 = (const float*)d_in[7];
    const float* bhh1 = (const float*)d_in[8];
    const float* fcW  = (const float*)d_in[9];
    const float* fcb  = (const float*)d_in[10];

    float* out = (float*)d_out;                       // [B,T,O]
    float* hid = out + (size_t)Bsz * Tt * Osz;        // [L,B,H]

    char* ws = (char*)d_ws;
    const size_t xp_off   = 0;
    const size_t hall_off = xp_off + (size_t)Bsz * Tt * G3 * 4;        // 100663296
    const size_t pbuf_off = hall_off + (size_t)Bsz * Tt * Hsz * 4;     // +33554432
    const size_t w0h_off  = pbuf_off + (size_t)2 * Bsz * Hsz * 8;      // +524288
    const size_t w1h_off  = w0h_off + (size_t)G3 * Isz * 2;            // +786432
    float*     xp    = (float*)(ws + xp_off);
    float*     hall  = (float*)(ws + hall_off);
    u32x2*     pbuf  = (u32x2*)(ws + pbuf_off);
    _Float16*  W0h   = (_Float16*)(ws + w0h_off);
    _Float16*  W1h   = (_Float16*)(ws + w1h_off);

    // convert gate-projection weights to f16 (exact casts, tiny)
    hipLaunchKernelGGL(f32_to_f16, dim3(128), dim3(256), 0, stream, Wih0, W0h, G3 * Isz / 4);
    hipLaunchKernelGGL(f32_to_f16, dim3(256), dim3(256), 0, stream, Wih1, W1h, G3 * Hsz / 4);

    // layer 0 input projection (f16 MFMA): xp = x @ Wih0^T + bih0
    hipLaunchKernelGGL(gemm_nt_mfma, dim3(G3 / 128, (Bsz * Tt) / 128), dim3(256), 0, stream,
                       x, W0h, bih0, xp, Bsz * Tt, G3, Isz);

    // layer 0 recurrence
    hipLaunchKernelGGL(init_pbuf, dim3(64), dim3(256), 0, stream, pbuf, G0_L0);
    hipLaunchKernelGGL(gru_rec, dim3(NBLK), dim3(TPB), 0, stream,
                       xp, Whh0, bhh0, hall, pbuf, hid, G0_L0);

    // layer 1 input projection (f16 MFMA): xp = hall @ Wih1^T + bih1
    hipLaunchKernelGGL(gemm_nt_mfma, dim3(G3 / 128, (Bsz * Tt) / 128), dim3(256), 0, stream,
                       hall, W1h, bih1, xp, Bsz * Tt, G3, Hsz);

    // layer 1 recurrence (overwrites hall)
    hipLaunchKernelGGL(init_pbuf, dim3(64), dim3(256), 0, stream, pbuf, G0_L1);
    hipLaunchKernelGGL(gru_rec, dim3(NBLK), dim3(TPB), 0, stream,
                       xp, Whh1, bhh1, hall, pbuf, hid + Bsz * Hsz, G0_L1);

    // FC (fp32, protects output precision): out = hall @ fcW^T + fcb
    hipLaunchKernelGGL(gemm_nt_bias, dim3(Osz / GN, (Bsz * Tt) / GM), dim3(256), 0, stream,
                       hall, fcW, fcb, out, Bsz * Tt, Osz, Hsz);
}

// Round 13
// 1972.633 us; speedup vs baseline: 1.2810x; 1.2810x over previous
//
#include <hip/hip_runtime.h>
#include <math.h>

// Problem constants
#define Bsz 32
#define Tt  512
#define Isz 256
#define Hsz 512
#define G3  1536
#define Osz 128

// Recurrence config (round-6 proven): 256 blocks = 32 batches x 8 col-groups;
// 512 threads/block. Device-coherent (sc0 sc1) gen-tagged (val,gen) pairs.
// Scalar fmaf inner loop (compiler-scheduled; pk_fma asm regressed, round 12).
#define NBLK 256
#define TPB  512
#define G0_L0 1u
#define G0_L1 4096u
#define POLL_GUARD (1 << 22)

typedef float f4  __attribute__((ext_vector_type(4)));
typedef float f32x4 __attribute__((ext_vector_type(4)));
typedef _Float16 half8_t __attribute__((ext_vector_type(8)));
typedef _Float16 half4_t __attribute__((ext_vector_type(4)));
typedef unsigned int u32;
typedef u32 u32x2 __attribute__((ext_vector_type(2)));

__device__ __forceinline__ float sigf(float x) { return 1.0f / (1.0f + expf(-x)); }

// ---------------- f32 -> f16 conversion (weights, exact RNE casts) ----------------
__global__ void f32_to_f16(const float* __restrict__ in, _Float16* __restrict__ out, int n4) {
    int i = threadIdx.x + blockIdx.x * blockDim.x;
    int stride = blockDim.x * gridDim.x;
    for (int k = i; k < n4; k += stride) {
        float4 v = reinterpret_cast<const float4*>(in)[k];
        half4_t o;
        o[0] = (_Float16)v.x; o[1] = (_Float16)v.y;
        o[2] = (_Float16)v.z; o[3] = (_Float16)v.w;
        reinterpret_cast<half4_t*>(out)[k] = o;
    }
}

// ---------------- init pbuf: slot0 = (h0=0, gen0), slot1 = invalid ----------------
__global__ void init_pbuf(u32x2* pbuf, u32 gen0) {
    int i = threadIdx.x + blockIdx.x * blockDim.x;
    const int n = Bsz * Hsz;
    for (; i < n; i += gridDim.x * blockDim.x) {
        pbuf[i]     = (u32x2){0u, gen0};
        pbuf[n + i] = (u32x2){0u, 0u};
    }
}

// ---------------- persistent GRU recurrence (one layer), batch-split ----------------
// Block (b,p): batch b, h-cols [p*64, p*64+64). Thread (jl=tid>>3, kc=tid&7):
// col j=p*64+jl, k-range [kc*64, +64). 192 weight floats/thread (AGPR/unified
// file residency); each thread polls exactly one (val,gen) pair per step.
__global__ void __launch_bounds__(TPB, 2) gru_rec(
    const float* __restrict__ xp,    // [B*T, 3H] (includes b_ih)
    const float* __restrict__ Whh,   // [3H, H]
    const float* __restrict__ bhh,   // [3H]
    float* __restrict__ hall,        // [B*T, H]
    u32x2* __restrict__ pbuf,        // [2][B*H] (val,gen)
    float* __restrict__ hid_out,     // [B*H]
    u32 g0)
{
    const int tid = threadIdx.x;
    const int b   = blockIdx.x & 31;
    const int p   = blockIdx.x >> 5;
    const int jl  = tid >> 3;
    const int kc  = tid & 7;
    const int j   = p * 64 + jl;

    __shared__ float hsh[8 * 68];   // h of batch b, 68-padded chunks

    // ---- load weights: rows {g*H+j}, k in [kc*64, +64)  -> 48 f4 = 192 floats ----
    f4 wreg[3][16];
    #pragma unroll
    for (int g = 0; g < 3; ++g) {
        const float* wp = Whh + (size_t)(g * Hsz + j) * Hsz + kc * 64;
        #pragma unroll
        for (int q = 0; q < 16; ++q)
            wreg[g][q] = *reinterpret_cast<const f4*>(wp + q * 4);
    }
    #pragma unroll
    for (int g = 0; g < 3; ++g)
        #pragma unroll
        for (int q = 0; q < 16; ++q)
            asm volatile("" : "+v"(wreg[g][q]));

    const float bh0 = bhh[0 * Hsz + j];
    const float bh1 = bhh[1 * Hsz + j];
    const float bh2 = bhh[2 * Hsz + j];

    for (int t = 0; t < Tt; ++t) {
        const u32 rg = g0 + (u32)t;
        const u32 wg = rg + 1u;
        const u32x2* src = pbuf + (size_t)(t & 1) * (Bsz * Hsz) + b * Hsz;
        u32x2*       dst = pbuf + (size_t)((t + 1) & 1) * (Bsz * Hsz) + b * Hsz;

        // xp for owner lanes (plain cached loads; issued before poll)
        float xr = 0.f, xz = 0.f, xn = 0.f;
        if (kc == 0) {
            const float* pp = xp + (size_t)(b * Tt + t) * G3;
            xr = pp[j];
            xz = pp[Hsz + j];
            xn = pp[2 * Hsz + j];
        }

        // ---- poll own pair (1 per thread), stage to LDS ----
        {
            const u32x2* sp = src + tid;
            int guard = 0;
            for (;;) {
                u32x2 pr;
                asm volatile("global_load_dwordx2 %0, %1, off sc0 sc1\n\t"
                             "s_waitcnt vmcnt(0)"
                             : "=&v"(pr) : "v"(sp) : "memory");
                if (__all(pr[1] == rg) || ++guard > POLL_GUARD) {
                    hsh[(tid >> 6) * 68 + (tid & 63)] = __uint_as_float(pr[0]);
                    break;
                }
                __builtin_amdgcn_s_sleep(1);
            }
        }
        __syncthreads();

        // ---- compute: 3 gate partials over k in [kc*64, +64) ----
        float a0 = 0.f, a1 = 0.f, a2 = 0.f;
        {
            const f4* hp = reinterpret_cast<const f4*>(hsh) + kc * 17;  // 68/4
            #pragma unroll
            for (int q = 0; q < 16; ++q) {
                f4 hv4 = hp[q];
                a0 = fmaf(wreg[0][q][0], hv4[0], a0);
                a0 = fmaf(wreg[0][q][1], hv4[1], a0);
                a0 = fmaf(wreg[0][q][2], hv4[2], a0);
                a0 = fmaf(wreg[0][q][3], hv4[3], a0);
                a1 = fmaf(wreg[1][q][0], hv4[0], a1);
                a1 = fmaf(wreg[1][q][1], hv4[1], a1);
                a1 = fmaf(wreg[1][q][2], hv4[2], a1);
                a1 = fmaf(wreg[1][q][3], hv4[3], a1);
                a2 = fmaf(wreg[2][q][0], hv4[0], a2);
                a2 = fmaf(wreg[2][q][1], hv4[1], a2);
                a2 = fmaf(wreg[2][q][2], hv4[2], a2);
                a2 = fmaf(wreg[2][q][3], hv4[3], a2);
            }
        }

        // reduce across the 8 kc lanes (low 3 lane bits)
        #pragma unroll
        for (int off = 1; off < 8; off <<= 1) {
            a0 += __shfl_xor(a0, off, 64);
            a1 += __shfl_xor(a1, off, 64);
            a2 += __shfl_xor(a2, off, 64);
        }

        if (kc == 0) {
            float rr = sigf(xr + a0 + bh0);
            float zz = sigf(xz + a1 + bh1);
            float nn = tanhf(xn + rr * (a2 + bh2));
            float ho = hsh[(j >> 6) * 68 + (j & 63)];
            float hv = (1.0f - zz) * nn + zz * ho;
            u32x2 pk = (u32x2){__float_as_uint(hv), wg};
            asm volatile("global_store_dwordx2 %0, %1, off sc0 sc1"
                         :: "v"(dst + j), "v"(pk) : "memory");
            hall[(size_t)(b * Tt + t) * Hsz + j] = hv;
            if (t == Tt - 1) hid_out[b * Hsz + j] = hv;
        }

        __syncthreads();
    }
}

// ---------------- f16-MFMA GEMM: C[M,N] = A[M,K]_f32 * Wh[N,K]_f16^T + bias ----
// Block 256 thr = 4 waves (2x2), block tile 128x128, wave tile 64x64 (4x4 of
// 16x16 MFMA tiles). Fragments loaded directly from global (contiguous 16B per
// lane for both operands); A converted f32->f16 in-register.
__global__ void __launch_bounds__(256) gemm_nt_mfma(
    const float* __restrict__ A,        // [M,K] f32
    const _Float16* __restrict__ Wh,    // [N,K] f16
    const float* __restrict__ bias,     // [N]
    float* __restrict__ C,              // [M,N]
    int M, int N, int K)
{
    const int tid = threadIdx.x;
    const int l   = tid & 63;
    const int w   = tid >> 6;
    const int wm  = w >> 1, wn = w & 1;
    const int m0  = blockIdx.y * 128 + wm * 64;
    const int n0  = blockIdx.x * 128 + wn * 64;
    const int lr  = l & 15;
    const int lk  = (l >> 4) * 8;

    f32x4 acc[4][4];
    #pragma unroll
    for (int mt = 0; mt < 4; ++mt)
        #pragma unroll
        for (int nt = 0; nt < 4; ++nt)
            acc[mt][nt] = (f32x4){0.f, 0.f, 0.f, 0.f};

    for (int ks = 0; ks < K; ks += 32) {
        half8_t af[4], bf[4];
        #pragma unroll
        for (int mt = 0; mt < 4; ++mt) {
            const float* pa = A + (size_t)(m0 + mt * 16 + lr) * K + ks + lk;
            float4 v0 = *reinterpret_cast<const float4*>(pa);
            float4 v1 = *reinterpret_cast<const float4*>(pa + 4);
            half8_t h;
            h[0] = (_Float16)v0.x; h[1] = (_Float16)v0.y;
            h[2] = (_Float16)v0.z; h[3] = (_Float16)v0.w;
            h[4] = (_Float16)v1.x; h[5] = (_Float16)v1.y;
            h[6] = (_Float16)v1.z; h[7] = (_Float16)v1.w;
            af[mt] = h;
        }
        #pragma unroll
        for (int nt = 0; nt < 4; ++nt)
            bf[nt] = *reinterpret_cast<const half8_t*>(Wh + (size_t)(n0 + nt * 16 + lr) * K + ks + lk);
        #pragma unroll
        for (int mt = 0; mt < 4; ++mt)
            #pragma unroll
            for (int nt = 0; nt < 4; ++nt)
                acc[mt][nt] = __builtin_amdgcn_mfma_f32_16x16x32_f16(af[mt], bf[nt], acc[mt][nt], 0, 0, 0);
    }

    #pragma unroll
    for (int nt = 0; nt < 4; ++nt) {
        const int colg = n0 + nt * 16 + lr;
        const float bb = bias[colg];
        #pragma unroll
        for (int mt = 0; mt < 4; ++mt) {
            #pragma unroll
            for (int r = 0; r < 4; ++r) {
                int rowg = m0 + mt * 16 + (l >> 4) * 4 + r;
                C[(size_t)rowg * N + colg] = acc[mt][nt][r] + bb;
            }
        }
    }
}

// ---------------- fp32 GEMM (FC only): C = A * W^T + bias ----------------
#define GM 64
#define GN 64
#define GK 16
__global__ void __launch_bounds__(256) gemm_nt_bias(
    const float* __restrict__ A, const float* __restrict__ W,
    const float* __restrict__ bias, float* __restrict__ C,
    int M, int N, int K)
{
    __shared__ float As[GK][GM];
    __shared__ float Bs[GK][GN];
    const int tid = threadIdx.x;
    const int n0 = blockIdx.x * GN;
    const int m0 = blockIdx.y * GM;
    const int tn = tid & 15;
    const int tm = tid >> 4;
    const int lrow = tid >> 2;
    const int lkq  = tid & 3;

    float acc[4][4];
    #pragma unroll
    for (int i = 0; i < 4; ++i)
        #pragma unroll
        for (int jj = 0; jj < 4; ++jj) acc[i][jj] = 0.0f;

    for (int k0 = 0; k0 < K; k0 += GK) {
        float4 av = *reinterpret_cast<const float4*>(&A[(size_t)(m0 + lrow) * K + k0 + lkq * 4]);
        float4 wv = *reinterpret_cast<const float4*>(&W[(size_t)(n0 + lrow) * K + k0 + lkq * 4]);
        __syncthreads();
        As[lkq * 4 + 0][lrow] = av.x; As[lkq * 4 + 1][lrow] = av.y;
        As[lkq * 4 + 2][lrow] = av.z; As[lkq * 4 + 3][lrow] = av.w;
        Bs[lkq * 4 + 0][lrow] = wv.x; Bs[lkq * 4 + 1][lrow] = wv.y;
        Bs[lkq * 4 + 2][lrow] = wv.z; Bs[lkq * 4 + 3][lrow] = wv.w;
        __syncthreads();
        #pragma unroll
        for (int k = 0; k < GK; ++k) {
            float4 a4 = *reinterpret_cast<const float4*>(&As[k][tm * 4]);
            float4 b4 = *reinterpret_cast<const float4*>(&Bs[k][tn * 4]);
            acc[0][0] = fmaf(a4.x, b4.x, acc[0][0]); acc[0][1] = fmaf(a4.x, b4.y, acc[0][1]);
            acc[0][2] = fmaf(a4.x, b4.z, acc[0][2]); acc[0][3] = fmaf(a4.x, b4.w, acc[0][3]);
            acc[1][0] = fmaf(a4.y, b4.x, acc[1][0]); acc[1][1] = fmaf(a4.y, b4.y, acc[1][1]);
            acc[1][2] = fmaf(a4.y, b4.z, acc[1][2]); acc[1][3] = fmaf(a4.y, b4.w, acc[1][3]);
            acc[2][0] = fmaf(a4.z, b4.x, acc[2][0]); acc[2][1] = fmaf(a4.z, b4.y, acc[2][1]);
            acc[2][2] = fmaf(a4.z, b4.z, acc[2][2]); acc[2][3] = fmaf(a4.z, b4.w, acc[2][3]);
            acc[3][0] = fmaf(a4.w, b4.x, acc[3][0]); acc[3][1] = fmaf(a4.w, b4.y, acc[3][1]);
            acc[3][2] = fmaf(a4.w, b4.z, acc[3][2]); acc[3][3] = fmaf(a4.w, b4.w, acc[3][3]);
        }
    }

    float4 bb = *reinterpret_cast<const float4*>(&bias[n0 + tn * 4]);
    #pragma unroll
    for (int i = 0; i < 4; ++i) {
        int m = m0 + tm * 4 + i;
        float4 o;
        o.x = acc[i][0] + bb.x; o.y = acc[i][1] + bb.y;
        o.z = acc[i][2] + bb.z; o.w = acc[i][3] + bb.w;
        *reinterpret_cast<float4*>(&C[(size_t)m * N + n0 + tn * 4]) = o;
    }
}

// ---------------- host launcher ----------------
extern "C" void kernel_launch(void* const* d_in, const int* in_sizes, int n_in,
                              void* d_out, int out_size, void* d_ws, size_t ws_size,
                              hipStream_t stream) {
    (void)in_sizes; (void)n_in; (void)out_size; (void)ws_size;
    const float* x    = (const float*)d_in[0];
    const float* Wih0 = (const float*)d_in[1];
    const float* Whh0 = (const float*)d_in[2];
    const float* bih0 = (const float*)d_in[3];
    const float* bhh0 = (const float*)d_in[4];
    const float* Wih1 = (const float*)d_in[5];
    const float* Whh1 = (const float*)d_in[6];
    const float* bih1 = (const float*)d_in[7];
    const float* bhh1 = (const float*)d_in[8];
    const float* fcW  = (const float*)d_in[9];
    const float* fcb  = (const float*)d_in[10];

    float* out = (float*)d_out;                       // [B,T,O]
    float* hid = out + (size_t)Bsz * Tt * Osz;        // [L,B,H]

    char* ws = (char*)d_ws;
    const size_t xp_off   = 0;
    const size_t hall_off = xp_off + (size_t)Bsz * Tt * G3 * 4;
    const size_t pbuf_off = hall_off + (size_t)Bsz * Tt * Hsz * 4;
    const size_t w0h_off  = pbuf_off + (size_t)2 * Bsz * Hsz * 8;
    const size_t w1h_off  = w0h_off + (size_t)G3 * Isz * 2;
    float*     xp    = (float*)(ws + xp_off);
    float*     hall  = (float*)(ws + hall_off);
    u32x2*     pbuf  = (u32x2*)(ws + pbuf_off);
    _Float16*  W0h   = (_Float16*)(ws + w0h_off);
    _Float16*  W1h   = (_Float16*)(ws + w1h_off);

    // convert gate-projection weights to f16 (exact casts, tiny)
    hipLaunchKernelGGL(f32_to_f16, dim3(128), dim3(256), 0, stream, Wih0, W0h, G3 * Isz / 4);
    hipLaunchKernelGGL(f32_to_f16, dim3(256), dim3(256), 0, stream, Wih1, W1h, G3 * Hsz / 4);

    // layer 0 input projection (f16 MFMA): xp = x @ Wih0^T + bih0
    hipLaunchKernelGGL(gemm_nt_mfma, dim3(G3 / 128, (Bsz * Tt) / 128), dim3(256), 0, stream,
                       x, W0h, bih0, xp, Bsz * Tt, G3, Isz);

    // layer 0 recurrence
    hipLaunchKernelGGL(init_pbuf, dim3(64), dim3(256), 0, stream, pbuf, G0_L0);
    hipLaunchKernelGGL(gru_rec, dim3(NBLK), dim3(TPB), 0, stream,
                       xp, Whh0, bhh0, hall, pbuf, hid, G0_L0);

    // layer 1 input projection (f16 MFMA): xp = hall @ Wih1^T + bih1
    hipLaunchKernelGGL(gemm_nt_mfma, dim3(G3 / 128, (Bsz * Tt) / 128), dim3(256), 0, stream,
                       hall, W1h, bih1, xp, Bsz * Tt, G3, Hsz);

    // layer 1 recurrence (overwrites hall)
    hipLaunchKernelGGL(init_pbuf, dim3(64), dim3(256), 0, stream, pbuf, G0_L1);
    hipLaunchKernelGGL(gru_rec, dim3(NBLK), dim3(TPB), 0, stream,
                       xp, Whh1, bhh1, hall, pbuf, hid + Bsz * Hsz, G0_L1);

    // FC (fp32, protects output precision): out = hall @ fcW^T + fcb
    hipLaunchKernelGGL(gemm_nt_bias, dim3(Osz / GN, (Bsz * Tt) / GM), dim3(256), 0, stream,
                       hall, fcW, fcb, out, Bsz * Tt, Osz, Hsz);
}